// Round 3
// baseline (34240.741 us; speedup 1.0000x reference)
//
#include <hip/hip_runtime.h>
#include <hip/hip_bf16.h>
#include <math.h>

#define S_LEN 512
#define BATCH 32
#define HID   512
#define G4    2048   // 4*H
#define DIM   300
#define NHEAD 8
#define HDIM  128
#define CH    64     // timesteps per xg chunk
#define NCH   8

typedef __hip_bfloat16 bf16;

// ---------------- workspace layout (float offsets) ----------------
// xgc:    [2 dir][64 slot][2048 n][32 b]          8,388,608 f
// hcat0:  [32 b][512 s][1024]                    16,777,216 f
// hcat1:  [32 b][512 s][1024]                    16,777,216 f  (h0 [16384][300] aliases its start)
// Wp:     [3072 n][1024 k]                        3,145,728 f
// pb:     [3072]                                      3,072 f
// cT:     [2 dir][512 u][32 b]                       32,768 f
// hG:     [2 parity][2 dir][32 b][512 k]             65,536 f
// pooled: [32 b][1024]                               32,768 f
// bar:    256 u32 (grid-barrier state)                  256 f
// QKV bf16 (3 * 16,777,216 elems = 25,165,824 float-slots) aliases [xgc + hcat0] exactly.
#define OFF_XGC   0ull
#define OFF_HCAT0 8388608ull
#define OFF_HCAT1 25165824ull
#define OFF_H0    25165824ull
#define OFF_WP    41943040ull
#define OFF_PB    45088768ull
#define OFF_CT    45091840ull
#define OFF_HG    45124608ull
#define OFF_POOL  45190144ull
#define OFF_BAR   45222912ull

// ---------------- embedding gather ----------------
__global__ void k_embed(const int* __restrict__ x, const float* __restrict__ emb,
                        float* __restrict__ h0)
{
    int p = blockIdx.x;                 // p = b*512 + s
    int row = x[p];
    const float* src = emb + (size_t)row * DIM;
    float* dst = h0 + (size_t)p * DIM;
    for (int d = threadIdx.x; d < DIM; d += blockDim.x) dst[d] = src[d];
}

// ---------------- chunk input-projection GEMM ----------------
__global__ __launch_bounds__(256) void k_xgc(const float* __restrict__ A, int lda,
    const float* __restrict__ Wf, const float* __restrict__ Wb,
    const float* __restrict__ bihf, const float* __restrict__ bhhf,
    const float* __restrict__ bihb, const float* __restrict__ bhhb,
    float* __restrict__ xgc, int K, int c64)
{
    __shared__ float As[8][128];
    __shared__ float Bs[8][128];
    int tid = threadIdx.x;
    int dir = blockIdx.z;
    int m0 = blockIdx.y * 128, n0 = blockIdx.x * 128;
    const float* W  = dir ? Wb : Wf;
    const float* b1 = dir ? bihb : bihf;
    const float* b2 = dir ? bhhb : bhhf;
    int tx = tid & 15, ty = tid >> 4;

    float acc[8][8];
#pragma unroll
    for (int i = 0; i < 8; i++)
#pragma unroll
        for (int j = 0; j < 8; j++) acc[i][j] = 0.f;

    for (int k0 = 0; k0 < K; k0 += 8) {
#pragma unroll
        for (int e4 = 0; e4 < 4; e4++) {
            int e = tid * 4 + e4;
            int kl = e & 7, ml = e >> 3;
            int kk = k0 + kl;
            int m = m0 + ml;
            int slot = m >> 5, bb = m & 31;
            int s = dir ? (S_LEN - 1 - c64 - slot) : (c64 + slot);
            As[kl][ml] = (kk < K) ? A[((size_t)bb * S_LEN + s) * lda + kk] : 0.f;
            Bs[kl][ml] = (kk < K) ? W[(size_t)(n0 + ml) * K + kk] : 0.f;
        }
        __syncthreads();
#pragma unroll
        for (int k = 0; k < 8; k++) {
            float a[8], b[8];
#pragma unroll
            for (int i = 0; i < 8; i++) a[i] = As[k][ty + 16 * i];
#pragma unroll
            for (int j = 0; j < 8; j++) b[j] = Bs[k][tx + 16 * j];
#pragma unroll
            for (int i = 0; i < 8; i++)
#pragma unroll
                for (int j = 0; j < 8; j++) acc[i][j] += a[i] * b[j];
        }
        __syncthreads();
    }

#pragma unroll
    for (int i = 0; i < 8; i++) {
        int m = m0 + ty + 16 * i;
        int slot = m >> 5, bb = m & 31;
#pragma unroll
        for (int j = 0; j < 8; j++) {
            int n = n0 + tx + 16 * j;
            xgc[(((size_t)dir * CH + slot) * G4 + n) * BATCH + bb] =
                acc[i][j] + b1[n] + b2[n];
        }
    }
}

// ---------------- persistent recurrence: 64 steps, both dirs, grid barrier ----------------
// grid 256 WGs x 512 thr. WG = (dir, ublk of 4 units). Weights in LDS (swizzled).
// thread: ks = tid&15 (k-slice of 32), b = tid>>4. Reduce over ks via shfl_xor.
__global__ __launch_bounds__(512) void k_chunk(const float* __restrict__ xgc,
    const float* __restrict__ Whh_f, const float* __restrict__ Whh_b,
    float* __restrict__ hG, float* __restrict__ cT, float* __restrict__ hcat,
    unsigned int* __restrict__ bar, int c64)
{
    __shared__ float Wldsf[16 * 512];
    int wg = blockIdx.x;
    int dir = wg >> 7, ublk = wg & 127;
    int u0 = ublk * 4;
    const float* Whh = dir ? Whh_b : Whh_f;
    int tid = threadIdx.x;
    int ks = tid & 15, b = tid >> 4;
    int gid = wg & 7;

    // load weight slice: LDS row r = g*4+uu <- Whh[g*512 + u0+uu][k], k XOR-swizzled
#pragma unroll
    for (int j = 0; j < 16; j++) {
        int idx = tid + 512 * j;
        int r = idx >> 9, k = idx & 511;
        int grow = (r >> 2) * HID + u0 + (r & 3);
        int kp = k ^ (((k >> 5) & 7) << 2);
        Wldsf[r * 512 + kp] = Whh[(size_t)grow * HID + k];
    }
    __syncthreads();

    const float4* Wl4 = (const float4*)Wldsf;
    int ks7 = ks & 7;

    float c_reg = 0.f;
    size_t ci = 0;
    if (ks < 4) {
        ci = ((size_t)dir * HID + u0 + ks) * BATCH + b;
        if (c64 > 0) c_reg = cT[ci];
    }

    for (int i = 0; i < CH; i++) {
        int tt = c64 + i;
        int s_cur = dir ? (S_LEN - 1 - tt) : tt;

        float xv0 = 0.f, xv1 = 0.f, xv2 = 0.f, xv3 = 0.f;
        if (ks < 4) {
            size_t xb = (((size_t)dir * CH + i) * G4) * BATCH + b;
            xv0 = xgc[xb + (size_t)(0 * HID + u0 + ks) * BATCH];
            xv1 = xgc[xb + (size_t)(1 * HID + u0 + ks) * BATCH];
            xv2 = xgc[xb + (size_t)(2 * HID + u0 + ks) * BATCH];
            xv3 = xgc[xb + (size_t)(3 * HID + u0 + ks) * BATCH];
        }

        float rsum[16];
#pragma unroll
        for (int r = 0; r < 16; r++) rsum[r] = 0.f;

        if (tt > 0) {
            int pr = (tt & 1) ^ 1;
            const float4* hp =
                (const float4*)(hG + ((size_t)(pr * 2 + dir) * BATCH + b) * HID) + ks * 8;
            float4 hh[8];
#pragma unroll
            for (int j = 0; j < 8; j++) hh[j] = hp[j];
#pragma unroll
            for (int r = 0; r < 16; r++) {
                float a = 0.f;
#pragma unroll
                for (int j = 0; j < 8; j++) {
                    float4 w = Wl4[r * 128 + ks * 8 + (j ^ ks7)];
                    a += w.x * hh[j].x + w.y * hh[j].y + w.z * hh[j].z + w.w * hh[j].w;
                }
                rsum[r] = a;
            }
            // in-wave butterfly over the 16 ks lanes
#pragma unroll
            for (int m = 1; m < 16; m <<= 1)
#pragma unroll
                for (int r = 0; r < 16; r++)
                    rsum[r] += __shfl_xor(rsum[r], m);
        }

        if (ks < 4) {
            int uu = ks;
            float g0 = 0.f, g1 = 0.f, g2 = 0.f, g3 = 0.f;
            if (tt > 0) {
                g0 = uu == 0 ? rsum[0]  : uu == 1 ? rsum[1]  : uu == 2 ? rsum[2]  : rsum[3];
                g1 = uu == 0 ? rsum[4]  : uu == 1 ? rsum[5]  : uu == 2 ? rsum[6]  : rsum[7];
                g2 = uu == 0 ? rsum[8]  : uu == 1 ? rsum[9]  : uu == 2 ? rsum[10] : rsum[11];
                g3 = uu == 0 ? rsum[12] : uu == 1 ? rsum[13] : uu == 2 ? rsum[14] : rsum[15];
            }
            g0 += xv0; g1 += xv1; g2 += xv2; g3 += xv3;
            float si = 1.f / (1.f + expf(-g0));
            float sf = 1.f / (1.f + expf(-g1));
            float so = 1.f / (1.f + expf(-g3));
            float cn = sf * c_reg + si * tanhf(g2);
            float hn = so * tanhf(cn);
            c_reg = cn;
            int pw = tt & 1;
            hG[((size_t)(pw * 2 + dir) * BATCH + b) * HID + u0 + uu] = hn;
            hcat[((size_t)b * S_LEN + s_cur) * 1024 + dir * HID + u0 + uu] = hn;
        }

        // ---- grid barrier (two-level, monotone counters) ----
        __syncthreads();
        if (tid == 0) {
            unsigned tgt = (unsigned)(i + 1);
            unsigned old = __hip_atomic_fetch_add(&bar[32 + gid * 16], 1u,
                                                  __ATOMIC_ACQ_REL, __HIP_MEMORY_SCOPE_AGENT);
            if (old == 32u * tgt - 1u) {
                unsigned r2 = __hip_atomic_fetch_add(&bar[16], 1u,
                                                     __ATOMIC_ACQ_REL, __HIP_MEMORY_SCOPE_AGENT);
                if (r2 == 8u * tgt - 1u)
                    __hip_atomic_store(&bar[0], tgt, __ATOMIC_RELEASE, __HIP_MEMORY_SCOPE_AGENT);
            }
            while (__hip_atomic_load(&bar[0], __ATOMIC_ACQUIRE, __HIP_MEMORY_SCOPE_AGENT) < tgt)
                __builtin_amdgcn_s_sleep(2);
        }
        __syncthreads();
    }
    if (ks < 4) cT[ci] = c_reg;
}

// ---------------- pack Wq/Wk/Wv -> Wp[3072][1024] + packed bias ----------------
__global__ void k_pack(const float* __restrict__ Wq, const float* __restrict__ Wk,
                       const float* __restrict__ Wv, const float* __restrict__ bq,
                       const float* __restrict__ bk, const float* __restrict__ bv,
                       float* __restrict__ Wp, float* __restrict__ pb)
{
    size_t i = (size_t)blockIdx.x * 256 + threadIdx.x;
    if (i < 3ull * 1024 * 1024) {
        int tt = (int)(i >> 20);
        int w  = (int)(i & 1048575);
        int n  = w >> 10;      // h*128+e
        int d  = w & 1023;
        int hh = n >> 7, e = n & 127;
        const float* W = (tt == 0) ? Wq : (tt == 1 ? Wk : Wv);
        Wp[i] = W[((size_t)hh * 1024 + d) * 128 + e];
    }
    if (i < 3072) {
        int tt = (int)(i >> 10), w = (int)(i & 1023);
        const float* bb = (tt == 0) ? bq : (tt == 1 ? bk : bv);
        pb[i] = bb[w];
    }
}

// ---------------- QKV GEMM (f32 compute, bf16 out) ----------------
__global__ __launch_bounds__(256) void k_qkv(const float* __restrict__ A,
    const float* __restrict__ Wp, const float* __restrict__ pb,
    bf16* __restrict__ Qout)
{
    __shared__ float As[8][128];
    __shared__ float Bs[8][128];
    int tid = threadIdx.x;
    int m0 = blockIdx.y * 128, n0 = blockIdx.x * 128;
    int tx = tid & 15, ty = tid >> 4;

    float acc[8][8];
#pragma unroll
    for (int i = 0; i < 8; i++)
#pragma unroll
        for (int j = 0; j < 8; j++) acc[i][j] = 0.f;

    for (int k0 = 0; k0 < 1024; k0 += 8) {
#pragma unroll
        for (int e4 = 0; e4 < 4; e4++) {
            int e = tid * 4 + e4;
            int kl = e & 7, ml = e >> 3;
            int kk = k0 + kl;
            As[kl][ml] = A[(size_t)(m0 + ml) * 1024 + kk];
            Bs[kl][ml] = Wp[(size_t)(n0 + ml) * 1024 + kk];
        }
        __syncthreads();
#pragma unroll
        for (int k = 0; k < 8; k++) {
            float a[8], b[8];
#pragma unroll
            for (int i = 0; i < 8; i++) a[i] = As[k][ty + 16 * i];
#pragma unroll
            for (int j = 0; j < 8; j++) b[j] = Bs[k][tx + 16 * j];
#pragma unroll
            for (int i = 0; i < 8; i++)
#pragma unroll
                for (int j = 0; j < 8; j++) acc[i][j] += a[i] * b[j];
        }
        __syncthreads();
    }

#pragma unroll
    for (int i = 0; i < 8; i++) {
        int m = m0 + ty + 16 * i;
        int b = m >> 9, s = m & 511;
#pragma unroll
        for (int j = 0; j < 8; j++) {
            int n = n0 + tx + 16 * j;
            int tt = n >> 10, w = n & 1023, hh = w >> 7, e = w & 127;
            float v = acc[i][j] + pb[n];
            Qout[(size_t)tt * 16777216ull +
                 ((size_t)(b * NHEAD + hh) * S_LEN + s) * HDIM + e] = __float2bfloat16(v);
        }
    }
}

// ---------------- attention: softmax column-weights -> pooled ----------------
__global__ __launch_bounds__(256) void k_attn(const bf16* __restrict__ Q,
    const bf16* __restrict__ K, const bf16* __restrict__ V,
    float* __restrict__ pooled)
{
    int bh = blockIdx.x;
    int b = bh >> 3, h = bh & 7;
    const bf16* Qb = Q + (size_t)bh * S_LEN * HDIM;
    const bf16* Kb = K + (size_t)bh * S_LEN * HDIM;
    const bf16* Vb = V + (size_t)bh * S_LEN * HDIM;

    __shared__ float Qs[16][HDIM];
    __shared__ float Ss[16][S_LEN + 4];
    __shared__ float wsum[S_LEN];

    int tid = threadIdx.x;
    for (int t = tid; t < S_LEN; t += 256) wsum[t] = 0.f;
    const float SC = 0.08838834764831845f;   // 1/sqrt(128)

    for (int rb = 0; rb < 32; rb++) {
        __syncthreads();
        for (int e = tid; e < 16 * HDIM; e += 256) {
            int rr = e >> 7, ee = e & 127;
            Qs[rr][ee] = __bfloat162float(Qb[(size_t)(rb * 16 + rr) * HDIM + ee]);
        }
        __syncthreads();
        float acc0[16], acc1[16];
#pragma unroll
        for (int r = 0; r < 16; r++) { acc0[r] = 0.f; acc1[r] = 0.f; }
        const bf16* k0p = Kb + (size_t)tid * HDIM;
        const bf16* k1p = Kb + (size_t)(tid + 256) * HDIM;
        for (int k = 0; k < HDIM; k += 4) {
            short4 r0 = *(const short4*)(k0p + k);
            short4 r1 = *(const short4*)(k1p + k);
            float k0x = __bfloat162float(*(const bf16*)&r0.x);
            float k0y = __bfloat162float(*(const bf16*)&r0.y);
            float k0z = __bfloat162float(*(const bf16*)&r0.z);
            float k0w = __bfloat162float(*(const bf16*)&r0.w);
            float k1x = __bfloat162float(*(const bf16*)&r1.x);
            float k1y = __bfloat162float(*(const bf16*)&r1.y);
            float k1z = __bfloat162float(*(const bf16*)&r1.z);
            float k1w = __bfloat162float(*(const bf16*)&r1.w);
#pragma unroll
            for (int r = 0; r < 16; r++) {
                float4 q = *(const float4*)&Qs[r][k];
                acc0[r] += q.x * k0x + q.y * k0y + q.z * k0z + q.w * k0w;
                acc1[r] += q.x * k1x + q.y * k1y + q.z * k1z + q.w * k1w;
            }
        }
#pragma unroll
        for (int r = 0; r < 16; r++) {
            Ss[r][tid] = acc0[r];
            Ss[r][tid + 256] = acc1[r];
        }
        __syncthreads();
        {
            int r = tid >> 4, l = tid & 15;
            float m = -1e30f;
            for (int t = l; t < S_LEN; t += 16) m = fmaxf(m, Ss[r][t]);
#pragma unroll
            for (int o = 1; o < 16; o <<= 1) m = fmaxf(m, __shfl_xor(m, o));
            float sum = 0.f;
            for (int t = l; t < S_LEN; t += 16) {
                float p = expf((Ss[r][t] - m) * SC);
                Ss[r][t] = p;
                sum += p;
            }
#pragma unroll
            for (int o = 1; o < 16; o <<= 1) sum += __shfl_xor(sum, o);
            float inv = 1.f / sum;
            for (int t = l; t < S_LEN; t += 16) Ss[r][t] *= inv;
        }
        __syncthreads();
        for (int t = tid; t < S_LEN; t += 256) {
            float s = 0.f;
#pragma unroll
            for (int rr = 0; rr < 16; rr++) s += Ss[rr][t];
            wsum[t] += s;
        }
    }
    __syncthreads();

    if (tid < HDIM) {
        float a = 0.f;
        for (int t = 0; t < S_LEN; t++)
            a += wsum[t] * __bfloat162float(Vb[(size_t)t * HDIM + tid]);
        pooled[(size_t)b * 1024 + h * HDIM + tid] = a * (1.0f / S_LEN);
    }
}

// ---------------- final FC ----------------
__global__ void k_fc(const float* __restrict__ pooled, const float* __restrict__ Wfc,
                     const float* __restrict__ bfc, float* __restrict__ out)
{
    int j = threadIdx.x;
    if (j < 96) {
        int b = j / 3, o = j - b * 3;
        float a = bfc[o];
        for (int k = 0; k < 1024; k++)
            a += pooled[(size_t)b * 1024 + k] * Wfc[(size_t)o * 1024 + k];
        out[j] = a;
    }
}

// ---------------- launch ----------------
extern "C" void kernel_launch(void* const* d_in, const int* in_sizes, int n_in,
                              void* d_out, int out_size, void* d_ws, size_t ws_size,
                              hipStream_t stream)
{
    const int*   x     = (const int*)d_in[0];
    const float* emb   = (const float*)d_in[1];
    const float* Wih0f = (const float*)d_in[2];
    const float* Whh0f = (const float*)d_in[3];
    const float* bih0f = (const float*)d_in[4];
    const float* bhh0f = (const float*)d_in[5];
    const float* Wih0b = (const float*)d_in[6];
    const float* Whh0b = (const float*)d_in[7];
    const float* bih0b = (const float*)d_in[8];
    const float* bhh0b = (const float*)d_in[9];
    const float* Wih1f = (const float*)d_in[10];
    const float* Whh1f = (const float*)d_in[11];
    const float* bih1f = (const float*)d_in[12];
    const float* bhh1f = (const float*)d_in[13];
    const float* Wih1b = (const float*)d_in[14];
    const float* Whh1b = (const float*)d_in[15];
    const float* bih1b = (const float*)d_in[16];
    const float* bhh1b = (const float*)d_in[17];
    const float* Wq    = (const float*)d_in[18];
    const float* bq    = (const float*)d_in[19];
    const float* Wk    = (const float*)d_in[20];
    const float* bk    = (const float*)d_in[21];
    const float* Wv    = (const float*)d_in[22];
    const float* bv    = (const float*)d_in[23];
    const float* Wfc   = (const float*)d_in[24];
    const float* bfc   = (const float*)d_in[25];

    float* ws     = (float*)d_ws;
    float* xgc    = ws + OFF_XGC;
    float* hcat0  = ws + OFF_HCAT0;
    float* hcat1  = ws + OFF_HCAT1;
    float* h0     = ws + OFF_H0;
    float* Wp     = ws + OFF_WP;
    float* pb     = ws + OFF_PB;
    float* cT     = ws + OFF_CT;
    float* hG     = ws + OFF_HG;
    float* pooled = ws + OFF_POOL;
    unsigned int* bar = (unsigned int*)(ws + OFF_BAR);
    bf16*  Qbf    = (bf16*)ws;                 // aliases xgc+hcat0 (dead by then)
    bf16*  Kbf    = Qbf + 16777216ull;
    bf16*  Vbf    = Qbf + 33554432ull;

    dim3 blk(256);

    k_embed<<<BATCH * S_LEN, 128, 0, stream>>>(x, emb, h0);
    k_pack<<<12288, 256, 0, stream>>>(Wq, Wk, Wv, bq, bk, bv, Wp, pb);

    // ---- layer 0 ----
    for (int c = 0; c < NCH; c++) {
        k_xgc<<<dim3(16, 16, 2), blk, 0, stream>>>(h0, DIM, Wih0f, Wih0b,
            bih0f, bhh0f, bih0b, bhh0b, xgc, DIM, c * CH);
        hipMemsetAsync(bar, 0, 1024, stream);
        k_chunk<<<256, 512, 0, stream>>>(xgc, Whh0f, Whh0b, hG, cT, hcat0, bar, c * CH);
    }
    // ---- layer 1 ----
    for (int c = 0; c < NCH; c++) {
        k_xgc<<<dim3(16, 16, 2), blk, 0, stream>>>(hcat0, 1024, Wih1f, Wih1b,
            bih1f, bhh1f, bih1b, bhh1b, xgc, 1024, c * CH);
        hipMemsetAsync(bar, 0, 1024, stream);
        k_chunk<<<256, 512, 0, stream>>>(xgc, Whh1f, Whh1b, hG, cT, hcat1, bar, c * CH);
    }

    // ---- attention ----
    k_qkv<<<dim3(24, 128), blk, 0, stream>>>(hcat1, Wp, pb, Qbf);
    k_attn<<<256, blk, 0, stream>>>(Qbf, Kbf, Vbf, pooled);
    k_fc<<<1, 128, 0, stream>>>(pooled, Wfc, bfc, (float*)d_out);
}